// Round 4
// baseline (421.479 us; speedup 1.0000x reference)
//
#include <hip/hip_runtime.h>
#include <hip/hip_bf16.h>
#include <float.h>

#define BB 8
#define NNq 8192
#define SSk 2048
#define CIN 512
#define OC 256
#define NR (BB * NNq)   // 65536 total rows (b*N+n)
#define NSTATB 256      // stats partial blocks

typedef __attribute__((ext_vector_type(8))) short bf16x8;
typedef __attribute__((ext_vector_type(4))) float f32x4;

__device__ __forceinline__ unsigned short f2bf(float f) {
  union { __hip_bfloat16 h; unsigned short u; } v;
  v.h = __float2bfloat16(f);
  return v.u;
}

// ---------------------------------------------------------------- prep: hq = (x,y,z,|q|^2) with np rounding
__global__ void k_prep_hq(const float* __restrict__ xyz2, float4* __restrict__ hq) {
  int i = blockIdx.x * 256 + threadIdx.x;
  if (i >= BB * SSk) return;
  float x = xyz2[i * 3 + 0], y = xyz2[i * 3 + 1], z = xyz2[i * 3 + 2];
  // sequential, no FMA: ((x*x + y*y) + z*z)
  float qq = __fadd_rn(__fadd_rn(__fmul_rn(x, x), __fmul_rn(y, y)), __fmul_rn(z, z));
  hq[i] = make_float4(x, y, z, qq);
}

// ---------------------------------------------------------------- knn: top-3 smallest, reference f32 rounding
__global__ void k_knn(const float* __restrict__ xyz1, const float4* __restrict__ hq,
                      int* __restrict__ idx3, float* __restrict__ w3) {
  int b = blockIdx.y;
  int n = blockIdx.x * 256 + threadIdx.x;
  long base = (long)(b * NNq + n);
  float x = xyz1[base * 3 + 0], y = xyz1[base * 3 + 1], z = xyz1[base * 3 + 2];
  float pp = __fadd_rn(__fadd_rn(__fmul_rn(x, x), __fmul_rn(y, y)), __fmul_rn(z, z));
  const float4* __restrict__ h = hq + b * SSk;
  float e0 = FLT_MAX, e1 = FLT_MAX, e2 = FLT_MAX;
  int i0 = 0, i1 = 0, i2 = 0;
#pragma unroll 4
  for (int s = 0; s < SSk; ++s) {
    float4 q = h[s];
    // d = ((-2*(x*qx + y*qy + z*qz)) + pp) + qq   -- exact np op order, no FMA
    float t = __fadd_rn(__fadd_rn(__fmul_rn(x, q.x), __fmul_rn(y, q.y)), __fmul_rn(z, q.z));
    float d = __fadd_rn(__fadd_rn(__fmul_rn(-2.0f, t), pp), q.w);
    if (d < e2) {
      if (d < e1) {
        e2 = e1; i2 = i1;
        if (d < e0) { e1 = e0; i1 = i0; e0 = d; i0 = s; }
        else        { e1 = d; i1 = s; }
      } else { e2 = d; i2 = s; }
    }
  }
  float r0 = 1.f / (e0 + 1e-8f), r1 = 1.f / (e1 + 1e-8f), r2 = 1.f / (e2 + 1e-8f);
  float rs = r0 + r1 + r2;
  idx3[base * 3 + 0] = i0; idx3[base * 3 + 1] = i1; idx3[base * 3 + 2] = i2;
  w3[base * 3 + 0] = r0 / rs; w3[base * 3 + 1] = r1 / rs; w3[base * 3 + 2] = r2 / rs;
}

// ---------------------------------------------------------------- transpose points1 -> xb[:,0:256] (bf16)
__global__ void k_tr_p1(const float* __restrict__ p1, __hip_bfloat16* __restrict__ xb) {
  __shared__ float tile[32][33];
  int b = blockIdx.z, c0 = blockIdx.y * 32, n0 = blockIdx.x * 32;
  int tx = threadIdx.x & 31, ty = threadIdx.x >> 5;   // 32x8
#pragma unroll
  for (int r = 0; r < 32; r += 8)
    tile[ty + r][tx] = p1[((long)(b * 256 + c0 + ty + r)) * NNq + n0 + tx];
  __syncthreads();
#pragma unroll
  for (int r = 0; r < 32; r += 8)
    xb[((long)(b * NNq + n0 + ty + r)) * CIN + c0 + tx] = __float2bfloat16(tile[tx][ty + r]);
}

// ---------------------------------------------------------------- transpose points2 -> p2t [B][S][256] f32
__global__ void k_tr_p2(const float* __restrict__ p2, float* __restrict__ p2t) {
  __shared__ float tile[32][33];
  int b = blockIdx.z, c0 = blockIdx.y * 32, s0 = blockIdx.x * 32;
  int tx = threadIdx.x & 31, ty = threadIdx.x >> 5;
#pragma unroll
  for (int r = 0; r < 32; r += 8)
    tile[ty + r][tx] = p2[((long)(b * 256 + c0 + ty + r)) * SSk + s0 + tx];
  __syncthreads();
#pragma unroll
  for (int r = 0; r < 32; r += 8)
    p2t[((long)(b * SSk + s0 + ty + r)) * 256 + c0 + tx] = tile[tx][ty + r];
}

// ---------------------------------------------------------------- gather + weighted interp -> xb[:,256:512]
__global__ void k_gather(const float* __restrict__ p2t, const int* __restrict__ idx3,
                         const float* __restrict__ w3, __hip_bfloat16* __restrict__ xb) {
  int b = blockIdx.y;
  int wid = threadIdx.x >> 6, lane = threadIdx.x & 63;
  int n = blockIdx.x * 4 + wid;                       // one wave per n
  long o = (long)(b * NNq + n) * 3;
  int i0 = idx3[o], i1 = idx3[o + 1], i2 = idx3[o + 2];
  float w0 = w3[o], w1 = w3[o + 1], w2 = w3[o + 2];
  const float4* r0 = (const float4*)(p2t + ((long)(b * SSk + i0)) * 256);
  const float4* r1 = (const float4*)(p2t + ((long)(b * SSk + i1)) * 256);
  const float4* r2 = (const float4*)(p2t + ((long)(b * SSk + i2)) * 256);
  float4 a = r0[lane], c = r1[lane], d = r2[lane];
  float vx = w0 * a.x + w1 * c.x + w2 * d.x;
  float vy = w0 * a.y + w1 * c.y + w2 * d.y;
  float vz = w0 * a.z + w1 * c.z + w2 * d.z;
  float vw = w0 * a.w + w1 * c.w + w2 * d.w;
  ushort4 u;
  u.x = f2bf(vx); u.y = f2bf(vy); u.z = f2bf(vz); u.w = f2bf(vw);
  *(ushort4*)((unsigned short*)xb + ((long)(b * NNq + n)) * CIN + 256 + lane * 4) = u;
}

// ---------------------------------------------------------------- f32 -> bf16 convert (weights)
__global__ void k_cvt(const float* __restrict__ in, __hip_bfloat16* __restrict__ out, int nelem) {
  int i = blockIdx.x * 256 + threadIdx.x;
  if (i < nelem) out[i] = __float2bfloat16(in[i]);
}

// ---------------------------------------------------------------- GEMM: Y[r][c] = sum_k X[r][k]*W[c][k]
// X:[NR][K] bf16 K-major, W:[256][K] bf16 K-major, Y:[NR][256] f32. m97 structure, BK=32.
template <int K>
__global__ __launch_bounds__(256) void k_gemm(const __hip_bfloat16* __restrict__ X,
                                              const __hip_bfloat16* __restrict__ W,
                                              float* __restrict__ Y) {
  constexpr int BK = 32;
  __shared__ __hip_bfloat16 xT[128 * BK];   // [row][k] row stride 32
  __shared__ __hip_bfloat16 wT[128 * BK];
  const int r0 = blockIdx.x * 128;
  const int c0 = blockIdx.y * 128;
  const int tid = threadIdx.x;
  const int wid = tid >> 6, lane = tid & 63;
  const int wr = wid >> 1, wc = wid & 1;    // 2x2 waves, each 64x64 out
  f32x4 acc[4][4] = {};

  for (int kt = 0; kt < K; kt += BK) {
#pragma unroll
    for (int jj = 0; jj < 2; ++jj) {
      int j = wid * 2 + jj;                 // 8 instrs cover 128 rows
      int row = j * 16 + (lane >> 2);
      const __hip_bfloat16* g = X + ((long)(r0 + row)) * K + kt + (lane & 3) * 8;
      __builtin_amdgcn_global_load_lds((const __attribute__((address_space(1))) void*)(const void*)g,
                                       (__attribute__((address_space(3))) void*)(void*)(xT + j * 512),
                                       16, 0, 0);
    }
#pragma unroll
    for (int jj = 0; jj < 2; ++jj) {
      int j = wid * 2 + jj;
      int row = j * 16 + (lane >> 2);
      const __hip_bfloat16* g = W + ((long)(c0 + row)) * K + kt + (lane & 3) * 8;
      __builtin_amdgcn_global_load_lds((const __attribute__((address_space(1))) void*)(const void*)g,
                                       (__attribute__((address_space(3))) void*)(void*)(wT + j * 512),
                                       16, 0, 0);
    }
    __syncthreads();

    bf16x8 af[4], bfr[4];
#pragma unroll
    for (int m = 0; m < 4; ++m) {
      int row = wr * 64 + m * 16 + (lane & 15);
      af[m] = *(const bf16x8*)(xT + row * BK + (lane >> 4) * 8);
    }
#pragma unroll
    for (int nn = 0; nn < 4; ++nn) {
      int row = wc * 64 + nn * 16 + (lane & 15);
      bfr[nn] = *(const bf16x8*)(wT + row * BK + (lane >> 4) * 8);
    }
#pragma unroll
    for (int m = 0; m < 4; ++m)
#pragma unroll
      for (int nn = 0; nn < 4; ++nn)
        acc[m][nn] = __builtin_amdgcn_mfma_f32_16x16x32_bf16(af[m], bfr[nn], acc[m][nn], 0, 0, 0);
    __syncthreads();
  }

#pragma unroll
  for (int m = 0; m < 4; ++m)
#pragma unroll
    for (int nn = 0; nn < 4; ++nn)
#pragma unroll
      for (int reg = 0; reg < 4; ++reg) {
        int r = r0 + wr * 64 + m * 16 + (lane >> 4) * 4 + reg;
        int c = c0 + wc * 64 + nn * 16 + (lane & 15);
        Y[(long)r * OC + c] = acc[m][nn][reg];
      }
}

// ---------------------------------------------------------------- BN stats: per-block partial sum & sumsq
__global__ void k_stats(const float* __restrict__ Y, float* __restrict__ part) {
  int o = threadIdx.x;                       // 256 channels
  int nper = NR / NSTATB;
  int n0 = blockIdx.x * nper;
  float s = 0.f, q = 0.f;
  for (int r = 0; r < nper; ++r) {
    float v = Y[(long)(n0 + r) * OC + o];
    s += v; q += v * v;
  }
  part[(long)blockIdx.x * 2 * OC + o] = s;
  part[(long)blockIdx.x * 2 * OC + OC + o] = q;
}

// ---------------------------------------------------------------- reduce partials, finalize BN scale/shift
__global__ void k_scalefix(const float* __restrict__ part, const float* __restrict__ g,
                           const float* __restrict__ be, float* __restrict__ st) {
  int o = threadIdx.x;
  float s = 0.f, q = 0.f;
  for (int b = 0; b < NSTATB; ++b) {
    s += part[(long)b * 2 * OC + o];
    q += part[(long)b * 2 * OC + OC + o];
  }
  float mean = s * (1.f / NR);
  float var = q * (1.f / NR) - mean * mean;
  float sc = g[o] * rsqrtf(var + 1e-5f);
  st[o] = sc;
  st[OC + o] = be[o] - mean * sc;
}

// ---------------------------------------------------------------- BN+ReLU -> bf16 (layer1 activations)
__global__ void k_bnrelu_bf16(const float* __restrict__ Y, const float* __restrict__ st,
                              __hip_bfloat16* __restrict__ Yb) {
  long i4 = (long)blockIdx.x * 256 + threadIdx.x;   // float4 index over [NR*256/4]
  float4 v = ((const float4*)Y)[i4];
  int c4 = (int)(i4 & 63);
  float4 sc = ((const float4*)st)[c4];
  float4 sh = ((const float4*)(st + OC))[c4];
  float ax = fmaxf(fmaf(v.x, sc.x, sh.x), 0.f);
  float ay = fmaxf(fmaf(v.y, sc.y, sh.y), 0.f);
  float az = fmaxf(fmaf(v.z, sc.z, sh.z), 0.f);
  float aw = fmaxf(fmaf(v.w, sc.w, sh.w), 0.f);
  ushort4 u; u.x = f2bf(ax); u.y = f2bf(ay); u.z = f2bf(az); u.w = f2bf(aw);
  ((ushort4*)Yb)[i4] = u;
}

// ---------------------------------------------------------------- BN+ReLU + transpose -> out [B][256][N] f32
__global__ void k_final(const float* __restrict__ Y, const float* __restrict__ st,
                        float* __restrict__ out) {
  __shared__ float tile[32][33];
  int b = blockIdx.z, o0 = blockIdx.y * 32, n0 = blockIdx.x * 32;
  int tx = threadIdx.x & 31, ty = threadIdx.x >> 5;
  float sc = st[o0 + tx], sh = st[OC + o0 + tx];
#pragma unroll
  for (int r = 0; r < 32; r += 8) {
    float v = Y[((long)(b * NNq + n0 + ty + r)) * OC + o0 + tx];
    tile[ty + r][tx] = fmaxf(fmaf(v, sc, sh), 0.f);
  }
  __syncthreads();
#pragma unroll
  for (int r = 0; r < 32; r += 8)
    out[((long)(b * 256 + o0 + ty + r)) * NNq + n0 + tx] = tile[tx][ty + r];
}

// ================================================================ launch
extern "C" void kernel_launch(void* const* d_in, const int* in_sizes, int n_in,
                              void* d_out, int out_size, void* d_ws, size_t ws_size,
                              hipStream_t stream) {
  const float* xyz1 = (const float*)d_in[0];
  const float* xyz2 = (const float*)d_in[1];
  const float* p1   = (const float*)d_in[2];
  const float* p2   = (const float*)d_in[3];
  const float* w1   = (const float*)d_in[4];
  // d_in[5] = b1 : cancels exactly under batch-norm mean subtraction
  const float* g1   = (const float*)d_in[6];
  const float* be1  = (const float*)d_in[7];
  const float* w2   = (const float*)d_in[8];
  // d_in[9] = b2 : cancels
  const float* g2   = (const float*)d_in[10];
  const float* be2  = (const float*)d_in[11];
  float* out = (float*)d_out;    // reference output dtype is float32

  char* ws = (char*)d_ws;
  // layout (bytes) -- sizes verified:
  //   XB   65536*512*2 = 67108864
  //   Y1   65536*256*4 = 67108864   (P2T 8*2048*256*4=16777216 aliases its head)
  //   HQ   16384*16    =   262144   (256KB -- was the round-1..3 bug: only 128KB reserved)
  //   IDX  65536*3*4   =   786432
  //   W3   65536*3*4   =   786432
  //   WB1  256*512*2   =   262144
  //   WB2  256*256*2   =   131072
  //   ST1/ST2 512*4    =     2048 each
  //   PART 256*512*4   =   524288
  const size_t OFF_XB   = 0;
  const size_t OFF_Y1   = 67108864;
  const size_t OFF_P2T  = OFF_Y1;                  // dead before GEMM1 writes Y1
  const size_t OFF_MISC = 134217728;
  const size_t OFF_HQ   = OFF_MISC + 0;
  const size_t OFF_IDX  = OFF_MISC + 262144;
  const size_t OFF_W3   = OFF_MISC + 1048576;
  const size_t OFF_WB1  = OFF_MISC + 1835008;
  const size_t OFF_WB2  = OFF_MISC + 2097152;
  const size_t OFF_ST1  = OFF_MISC + 2228224;
  const size_t OFF_ST2  = OFF_MISC + 2230272;
  const size_t OFF_PART = OFF_MISC + 2232320;      // ends MISC+2756608 (~137MB total)

  __hip_bfloat16* xb  = (__hip_bfloat16*)(ws + OFF_XB);
  float* y1           = (float*)(ws + OFF_Y1);
  float* y2           = (float*)(ws + OFF_Y1);     // alias: y1 dead once GEMM2 runs
  float* p2t          = (float*)(ws + OFF_P2T);
  float4* hq          = (float4*)(ws + OFF_HQ);
  int*   idx3         = (int*)(ws + OFF_IDX);
  float* w3           = (float*)(ws + OFF_W3);
  __hip_bfloat16* wb1 = (__hip_bfloat16*)(ws + OFF_WB1);
  __hip_bfloat16* wb2 = (__hip_bfloat16*)(ws + OFF_WB2);
  __hip_bfloat16* y1b = (__hip_bfloat16*)(ws + OFF_XB);   // alias: xb dead after GEMM1
  float* st1          = (float*)(ws + OFF_ST1);
  float* st2          = (float*)(ws + OFF_ST2);
  float* part         = (float*)(ws + OFF_PART);

  k_cvt<<<512, 256, 0, stream>>>(w1, wb1, 256 * 512);
  k_cvt<<<256, 256, 0, stream>>>(w2, wb2, 256 * 256);
  k_prep_hq<<<64, 256, 0, stream>>>(xyz2, hq);
  k_knn<<<dim3(NNq / 256, BB), 256, 0, stream>>>(xyz1, hq, idx3, w3);
  k_tr_p1<<<dim3(NNq / 32, 256 / 32, BB), 256, 0, stream>>>(p1, xb);
  k_tr_p2<<<dim3(SSk / 32, 256 / 32, BB), 256, 0, stream>>>(p2, p2t);
  k_gather<<<dim3(NNq / 4, BB), 256, 0, stream>>>(p2t, idx3, w3, xb);

  k_gemm<512><<<dim3(NR / 128, 2), 256, 0, stream>>>(xb, wb1, y1);
  k_stats<<<NSTATB, 256, 0, stream>>>(y1, part);
  k_scalefix<<<1, 256, 0, stream>>>(part, g1, be1, st1);
  k_bnrelu_bf16<<<(int)((long)NR * 256 / 4 / 256), 256, 0, stream>>>(y1, st1, y1b);

  k_gemm<256><<<dim3(NR / 128, 2), 256, 0, stream>>>(y1b, wb2, y2);
  k_stats<<<NSTATB, 256, 0, stream>>>(y2, part);
  k_scalefix<<<1, 256, 0, stream>>>(part, g2, be2, st2);
  k_final<<<dim3(NNq / 32, 256 / 32, BB), 256, 0, stream>>>(y2, st2, out);

  (void)in_sizes; (void)n_in; (void)out_size; (void)ws_size;
}

// Round 5
// 286.804 us; speedup vs baseline: 1.4696x; 1.4696x over previous
//
#include <hip/hip_runtime.h>
#include <hip/hip_bf16.h>
#include <float.h>

#define BB 8
#define NNq 8192
#define SSk 2048
#define CIN 512
#define OC 256
#define NR (BB * NNq)   // 65536 total rows (b*N+n)
#define NBX 512         // GEMM row-blocks = NR/128

typedef __attribute__((ext_vector_type(8))) short bf16x8;
typedef __attribute__((ext_vector_type(4))) float f32x4;

__device__ __forceinline__ unsigned short f2bf(float f) {
  union { __hip_bfloat16 h; unsigned short u; } v;
  v.h = __float2bfloat16(f);
  return v.u;
}

// ---------------------------------------------------------------- prep: hq = (x,y,z,|q|^2) with np rounding
__global__ void k_prep_hq(const float* __restrict__ xyz2, float4* __restrict__ hq) {
  int i = blockIdx.x * 256 + threadIdx.x;
  if (i >= BB * SSk) return;
  float x = xyz2[i * 3 + 0], y = xyz2[i * 3 + 1], z = xyz2[i * 3 + 2];
  float qq = __fadd_rn(__fadd_rn(__fmul_rn(x, x), __fmul_rn(y, y)), __fmul_rn(z, z));
  hq[i] = make_float4(x, y, z, qq);
}

// ---------------------------------------------------------------- knn: 64 queries/block, 4 waves x 512-chunk scan
__global__ __launch_bounds__(256, 4) void k_knn(const float* __restrict__ xyz1,
                                                const float4* __restrict__ hq,
                                                int* __restrict__ idx3, float* __restrict__ w3) {
  __shared__ float4 lhq[SSk];          // 32KB: whole candidate set for this batch
  __shared__ float  me[4][64][3];      // per-wave top-3 distances
  __shared__ int    mi[4][64][3];      // per-wave top-3 indices
  int b = blockIdx.y;
  int t = threadIdx.x;
  int lane = t & 63, w = t >> 6;

  const float4* __restrict__ hsrc = hq + (long)b * SSk;
#pragma unroll
  for (int j = 0; j < 8; ++j) lhq[t + j * 256] = hsrc[t + j * 256];

  int n = blockIdx.x * 64 + lane;
  long base = (long)(b * NNq + n);
  float x = xyz1[base * 3 + 0], y = xyz1[base * 3 + 1], z = xyz1[base * 3 + 2];
  float pp = __fadd_rn(__fadd_rn(__fmul_rn(x, x), __fmul_rn(y, y)), __fmul_rn(z, z));
  __syncthreads();

  float e0 = FLT_MAX, e1 = FLT_MAX, e2 = FLT_MAX;
  int i0 = 0, i1 = 0, i2 = 0;
  int s0 = w * 512;
#pragma unroll 4
  for (int i = 0; i < 512; ++i) {
    int s = s0 + i;
    float4 q = lhq[s];
    // d = ((-2*(x*qx + y*qy + z*qz)) + pp) + qq   -- exact np op order, no FMA
    float tt = __fadd_rn(__fadd_rn(__fmul_rn(x, q.x), __fmul_rn(y, q.y)), __fmul_rn(z, q.z));
    float d = __fadd_rn(__fadd_rn(__fmul_rn(-2.0f, tt), pp), q.w);
    if (d < e2) {
      if (d < e1) {
        e2 = e1; i2 = i1;
        if (d < e0) { e1 = e0; i1 = i0; e0 = d; i0 = s; }
        else        { e1 = d; i1 = s; }
      } else { e2 = d; i2 = s; }
    }
  }
  me[w][lane][0] = e0; me[w][lane][1] = e1; me[w][lane][2] = e2;
  mi[w][lane][0] = i0; mi[w][lane][1] = i1; mi[w][lane][2] = i2;
  __syncthreads();

  if (w == 0) {
    // merge waves 1..3 in chunk order (stable: strict < keeps lowest index on ties)
    for (int ww = 1; ww < 4; ++ww)
#pragma unroll
      for (int k = 0; k < 3; ++k) {
        float d = me[ww][lane][k]; int s = mi[ww][lane][k];
        if (d < e2) {
          if (d < e1) {
            e2 = e1; i2 = i1;
            if (d < e0) { e1 = e0; i1 = i0; e0 = d; i0 = s; }
            else        { e1 = d; i1 = s; }
          } else { e2 = d; i2 = s; }
        }
      }
    float r0 = 1.f / (e0 + 1e-8f), r1 = 1.f / (e1 + 1e-8f), r2 = 1.f / (e2 + 1e-8f);
    float rs = r0 + r1 + r2;
    idx3[base * 3 + 0] = i0; idx3[base * 3 + 1] = i1; idx3[base * 3 + 2] = i2;
    w3[base * 3 + 0] = r0 / rs; w3[base * 3 + 1] = r1 / rs; w3[base * 3 + 2] = r2 / rs;
  }
}

// ---------------------------------------------------------------- transpose points1 -> xb[:,0:256] (bf16)
__global__ void k_tr_p1(const float* __restrict__ p1, __hip_bfloat16* __restrict__ xb) {
  __shared__ float tile[32][33];
  int b = blockIdx.z, c0 = blockIdx.y * 32, n0 = blockIdx.x * 32;
  int tx = threadIdx.x & 31, ty = threadIdx.x >> 5;   // 32x8
#pragma unroll
  for (int r = 0; r < 32; r += 8)
    tile[ty + r][tx] = p1[((long)(b * 256 + c0 + ty + r)) * NNq + n0 + tx];
  __syncthreads();
#pragma unroll
  for (int r = 0; r < 32; r += 8)
    xb[((long)(b * NNq + n0 + ty + r)) * CIN + c0 + tx] = __float2bfloat16(tile[tx][ty + r]);
}

// ---------------------------------------------------------------- transpose points2 -> p2t [B][S][256] f32
__global__ void k_tr_p2(const float* __restrict__ p2, float* __restrict__ p2t) {
  __shared__ float tile[32][33];
  int b = blockIdx.z, c0 = blockIdx.y * 32, s0 = blockIdx.x * 32;
  int tx = threadIdx.x & 31, ty = threadIdx.x >> 5;
#pragma unroll
  for (int r = 0; r < 32; r += 8)
    tile[ty + r][tx] = p2[((long)(b * 256 + c0 + ty + r)) * SSk + s0 + tx];
  __syncthreads();
#pragma unroll
  for (int r = 0; r < 32; r += 8)
    p2t[((long)(b * SSk + s0 + ty + r)) * 256 + c0 + tx] = tile[tx][ty + r];
}

// ---------------------------------------------------------------- gather + weighted interp -> xb[:,256:512]
__global__ void k_gather(const float* __restrict__ p2t, const int* __restrict__ idx3,
                         const float* __restrict__ w3, __hip_bfloat16* __restrict__ xb) {
  int b = blockIdx.y;
  int wid = threadIdx.x >> 6, lane = threadIdx.x & 63;
  int n = blockIdx.x * 4 + wid;                       // one wave per n
  long o = (long)(b * NNq + n) * 3;
  int i0 = idx3[o], i1 = idx3[o + 1], i2 = idx3[o + 2];
  float w0 = w3[o], w1 = w3[o + 1], w2 = w3[o + 2];
  const float4* r0 = (const float4*)(p2t + ((long)(b * SSk + i0)) * 256);
  const float4* r1 = (const float4*)(p2t + ((long)(b * SSk + i1)) * 256);
  const float4* r2 = (const float4*)(p2t + ((long)(b * SSk + i2)) * 256);
  float4 a = r0[lane], c = r1[lane], d = r2[lane];
  float vx = w0 * a.x + w1 * c.x + w2 * d.x;
  float vy = w0 * a.y + w1 * c.y + w2 * d.y;
  float vz = w0 * a.z + w1 * c.z + w2 * d.z;
  float vw = w0 * a.w + w1 * c.w + w2 * d.w;
  ushort4 u;
  u.x = f2bf(vx); u.y = f2bf(vy); u.z = f2bf(vz); u.w = f2bf(vw);
  *(ushort4*)((unsigned short*)xb + ((long)(b * NNq + n)) * CIN + 256 + lane * 4) = u;
}

// ---------------------------------------------------------------- f32 -> bf16 convert (weights)
__global__ void k_cvt(const float* __restrict__ in, __hip_bfloat16* __restrict__ out, int nelem) {
  int i = blockIdx.x * 256 + threadIdx.x;
  if (i < nelem) out[i] = __float2bfloat16(in[i]);
}

// ---------------------------------------------------------------- GEMM + fused per-block BN partial stats
// X:[NR][K] bf16 K-major, W:[256][K] bf16 K-major, Y:[NR][256] f32.
// part: sums at part[ch*NBX+bx], sumsq at part[(256+ch)*NBX+bx]
template <int K>
__global__ __launch_bounds__(256) void k_gemm(const __hip_bfloat16* __restrict__ X,
                                              const __hip_bfloat16* __restrict__ W,
                                              float* __restrict__ Y,
                                              float* __restrict__ part) {
  constexpr int BK = 32;
  __shared__ __hip_bfloat16 xT[128 * BK];   // [row][k] row stride 32
  __shared__ __hip_bfloat16 wT[128 * BK];
  __shared__ float sb[4][4][16], qb[4][4][16];
  const int bx = blockIdx.x;
  const int r0 = bx * 128;
  const int c0 = blockIdx.y * 128;
  const int tid = threadIdx.x;
  const int wid = tid >> 6, lane = tid & 63;
  const int wr = wid >> 1, wc = wid & 1;    // 2x2 waves, each 64x64 out
  f32x4 acc[4][4] = {};

  for (int kt = 0; kt < K; kt += BK) {
#pragma unroll
    for (int jj = 0; jj < 2; ++jj) {
      int j = wid * 2 + jj;                 // 8 instrs cover 128 rows
      int row = j * 16 + (lane >> 2);
      const __hip_bfloat16* g = X + ((long)(r0 + row)) * K + kt + (lane & 3) * 8;
      __builtin_amdgcn_global_load_lds((const __attribute__((address_space(1))) void*)(const void*)g,
                                       (__attribute__((address_space(3))) void*)(void*)(xT + j * 512),
                                       16, 0, 0);
    }
#pragma unroll
    for (int jj = 0; jj < 2; ++jj) {
      int j = wid * 2 + jj;
      int row = j * 16 + (lane >> 2);
      const __hip_bfloat16* g = W + ((long)(c0 + row)) * K + kt + (lane & 3) * 8;
      __builtin_amdgcn_global_load_lds((const __attribute__((address_space(1))) void*)(const void*)g,
                                       (__attribute__((address_space(3))) void*)(void*)(wT + j * 512),
                                       16, 0, 0);
    }
    __syncthreads();

    bf16x8 af[4], bfr[4];
#pragma unroll
    for (int m = 0; m < 4; ++m) {
      int row = wr * 64 + m * 16 + (lane & 15);
      af[m] = *(const bf16x8*)(xT + row * BK + (lane >> 4) * 8);
    }
#pragma unroll
    for (int nn = 0; nn < 4; ++nn) {
      int row = wc * 64 + nn * 16 + (lane & 15);
      bfr[nn] = *(const bf16x8*)(wT + row * BK + (lane >> 4) * 8);
    }
#pragma unroll
    for (int m = 0; m < 4; ++m)
#pragma unroll
      for (int nn = 0; nn < 4; ++nn)
        acc[m][nn] = __builtin_amdgcn_mfma_f32_16x16x32_bf16(af[m], bfr[nn], acc[m][nn], 0, 0, 0);
    __syncthreads();
  }

  // C write
#pragma unroll
  for (int m = 0; m < 4; ++m)
#pragma unroll
    for (int nn = 0; nn < 4; ++nn)
#pragma unroll
      for (int reg = 0; reg < 4; ++reg) {
        int r = r0 + wr * 64 + m * 16 + (lane >> 4) * 4 + reg;
        int c = c0 + wc * 64 + nn * 16 + (lane & 15);
        Y[(long)r * OC + c] = acc[m][nn][reg];
      }

  // fused BN partial stats: per-channel sum & sumsq over this block's 128 rows
#pragma unroll
  for (int nn = 0; nn < 4; ++nn) {
    float s = 0.f, q = 0.f;
#pragma unroll
    for (int m = 0; m < 4; ++m)
#pragma unroll
      for (int reg = 0; reg < 4; ++reg) {
        float v = acc[m][nn][reg];
        s += v; q += v * v;
      }
    s += __shfl_xor(s, 16); s += __shfl_xor(s, 32);
    q += __shfl_xor(q, 16); q += __shfl_xor(q, 32);
    if (lane < 16) { sb[wid][nn][lane] = s; qb[wid][nn][lane] = q; }
  }
  __syncthreads();
  if (tid < 128) {
    int col = tid & 15, nn = (tid >> 4) & 3, wcc = (tid >> 6) & 1;
    float s = sb[wcc][nn][col] + sb[2 + wcc][nn][col];   // wid = wr*2+wc
    float q = qb[wcc][nn][col] + qb[2 + wcc][nn][col];
    int ch = c0 + wcc * 64 + nn * 16 + col;
    part[(long)ch * NBX + bx] = s;
    part[(long)(256 + ch) * NBX + bx] = q;
  }
}

// ---------------------------------------------------------------- reduce partials, finalize BN scale/shift
__global__ void k_scalefix(const float* __restrict__ part, const float* __restrict__ g,
                           const float* __restrict__ be, float* __restrict__ st) {
  int o = threadIdx.x;
  const float4* ps = (const float4*)(part + (long)o * NBX);
  const float4* pq = (const float4*)(part + (long)(256 + o) * NBX);
  float s = 0.f, q = 0.f;
#pragma unroll 8
  for (int i = 0; i < NBX / 4; ++i) {
    float4 a = ps[i], bq = pq[i];
    s += (a.x + a.y) + (a.z + a.w);
    q += (bq.x + bq.y) + (bq.z + bq.w);
  }
  float mean = s * (1.f / NR);
  float var = q * (1.f / NR) - mean * mean;
  float sc = g[o] * rsqrtf(var + 1e-5f);
  st[o] = sc;
  st[OC + o] = be[o] - mean * sc;
}

// ---------------------------------------------------------------- BN+ReLU -> bf16 (layer1 activations)
__global__ void k_bnrelu_bf16(const float* __restrict__ Y, const float* __restrict__ st,
                              __hip_bfloat16* __restrict__ Yb) {
  long i4 = (long)blockIdx.x * 256 + threadIdx.x;   // float4 index over [NR*256/4]
  float4 v = ((const float4*)Y)[i4];
  int c4 = (int)(i4 & 63);
  float4 sc = ((const float4*)st)[c4];
  float4 sh = ((const float4*)(st + OC))[c4];
  float ax = fmaxf(fmaf(v.x, sc.x, sh.x), 0.f);
  float ay = fmaxf(fmaf(v.y, sc.y, sh.y), 0.f);
  float az = fmaxf(fmaf(v.z, sc.z, sh.z), 0.f);
  float aw = fmaxf(fmaf(v.w, sc.w, sh.w), 0.f);
  ushort4 u; u.x = f2bf(ax); u.y = f2bf(ay); u.z = f2bf(az); u.w = f2bf(aw);
  ((ushort4*)Yb)[i4] = u;
}

// ---------------------------------------------------------------- BN+ReLU + transpose -> out [B][256][N] f32
__global__ void k_final(const float* __restrict__ Y, const float* __restrict__ st,
                        float* __restrict__ out) {
  __shared__ float tile[32][33];
  int b = blockIdx.z, o0 = blockIdx.y * 32, n0 = blockIdx.x * 32;
  int tx = threadIdx.x & 31, ty = threadIdx.x >> 5;
  float sc = st[o0 + tx], sh = st[OC + o0 + tx];
#pragma unroll
  for (int r = 0; r < 32; r += 8) {
    float v = Y[((long)(b * NNq + n0 + ty + r)) * OC + o0 + tx];
    tile[ty + r][tx] = fmaxf(fmaf(v, sc, sh), 0.f);
  }
  __syncthreads();
#pragma unroll
  for (int r = 0; r < 32; r += 8)
    out[((long)(b * 256 + o0 + ty + r)) * NNq + n0 + tx] = tile[tx][ty + r];
}

// ================================================================ launch
extern "C" void kernel_launch(void* const* d_in, const int* in_sizes, int n_in,
                              void* d_out, int out_size, void* d_ws, size_t ws_size,
                              hipStream_t stream) {
  const float* xyz1 = (const float*)d_in[0];
  const float* xyz2 = (const float*)d_in[1];
  const float* p1   = (const float*)d_in[2];
  const float* p2   = (const float*)d_in[3];
  const float* w1   = (const float*)d_in[4];
  // d_in[5] = b1 : cancels exactly under batch-norm mean subtraction
  const float* g1   = (const float*)d_in[6];
  const float* be1  = (const float*)d_in[7];
  const float* w2   = (const float*)d_in[8];
  // d_in[9] = b2 : cancels
  const float* g2   = (const float*)d_in[10];
  const float* be2  = (const float*)d_in[11];
  float* out = (float*)d_out;    // reference output dtype is float32

  char* ws = (char*)d_ws;
  // layout (bytes):
  //   XB   65536*512*2 = 67108864   (reused by Y1B after GEMM1)
  //   Y1   65536*256*4 = 67108864   (P2T 16MB aliases its head; Y2 aliases whole)
  //   HQ   16384*16    =   262144
  //   IDX  65536*3*4   =   786432   (dead after k_gather -> reused by PART 1MB)
  //   W3   65536*3*4   =   786432
  //   WB1  256*512*2   =   262144
  //   WB2  256*256*2   =   131072
  //   ST1/ST2 512*4    =     2048 each
  const size_t OFF_XB   = 0;
  const size_t OFF_Y1   = 67108864;
  const size_t OFF_P2T  = OFF_Y1;                  // dead before GEMM1 writes Y1
  const size_t OFF_MISC = 134217728;
  const size_t OFF_HQ   = OFF_MISC + 0;
  const size_t OFF_IDX  = OFF_MISC + 262144;
  const size_t OFF_W3   = OFF_MISC + 1048576;
  const size_t OFF_WB1  = OFF_MISC + 1835008;
  const size_t OFF_WB2  = OFF_MISC + 2097152;
  const size_t OFF_ST1  = OFF_MISC + 2228224;
  const size_t OFF_ST2  = OFF_MISC + 2230272;
  const size_t OFF_PART = OFF_IDX;                 // 1MB, aliases idx3+w3 (dead after k_gather)

  __hip_bfloat16* xb  = (__hip_bfloat16*)(ws + OFF_XB);
  float* y1           = (float*)(ws + OFF_Y1);
  float* y2           = (float*)(ws + OFF_Y1);     // alias: y1 dead once GEMM2 runs
  float* p2t          = (float*)(ws + OFF_P2T);
  float4* hq          = (float4*)(ws + OFF_HQ);
  int*   idx3         = (int*)(ws + OFF_IDX);
  float* w3           = (float*)(ws + OFF_W3);
  __hip_bfloat16* wb1 = (__hip_bfloat16*)(ws + OFF_WB1);
  __hip_bfloat16* wb2 = (__hip_bfloat16*)(ws + OFF_WB2);
  __hip_bfloat16* y1b = (__hip_bfloat16*)(ws + OFF_XB);   // alias: xb dead after GEMM1
  float* st1          = (float*)(ws + OFF_ST1);
  float* st2          = (float*)(ws + OFF_ST2);
  float* part         = (float*)(ws + OFF_PART);

  k_cvt<<<512, 256, 0, stream>>>(w1, wb1, 256 * 512);
  k_cvt<<<256, 256, 0, stream>>>(w2, wb2, 256 * 256);
  k_prep_hq<<<64, 256, 0, stream>>>(xyz2, hq);
  k_knn<<<dim3(NNq / 64, BB), 256, 0, stream>>>(xyz1, hq, idx3, w3);
  k_tr_p1<<<dim3(NNq / 32, 256 / 32, BB), 256, 0, stream>>>(p1, xb);
  k_tr_p2<<<dim3(SSk / 32, 256 / 32, BB), 256, 0, stream>>>(p2, p2t);
  k_gather<<<dim3(NNq / 4, BB), 256, 0, stream>>>(p2t, idx3, w3, xb);

  k_gemm<512><<<dim3(NBX, 2), 256, 0, stream>>>(xb, wb1, y1, part);
  k_scalefix<<<1, 256, 0, stream>>>(part, g1, be1, st1);
  k_bnrelu_bf16<<<(int)((long)NR * 256 / 4 / 256), 256, 0, stream>>>(y1, st1, y1b);

  k_gemm<256><<<dim3(NBX, 2), 256, 0, stream>>>(y1b, wb2, y2, part);
  k_scalefix<<<1, 256, 0, stream>>>(part, g2, be2, st2);
  k_final<<<dim3(NNq / 32, 256 / 32, BB), 256, 0, stream>>>(y2, st2, out);

  (void)in_sizes; (void)n_in; (void)out_size; (void)ws_size;
}

// Round 6
// 267.666 us; speedup vs baseline: 1.5746x; 1.0715x over previous
//
#include <hip/hip_runtime.h>
#include <hip/hip_bf16.h>
#include <float.h>

#define BB 8
#define NNq 8192
#define SSk 2048
#define CIN 512
#define OC 256
#define NR (BB * NNq)   // 65536 total rows (b*N+n)
#define NBX 512         // GEMM row-blocks = NR/128

typedef __attribute__((ext_vector_type(8))) short bf16x8;
typedef __attribute__((ext_vector_type(8))) unsigned short ushort8;
typedef __attribute__((ext_vector_type(4))) float f32x4;

__device__ __forceinline__ unsigned short f2bf(float f) {
  union { __hip_bfloat16 h; unsigned short u; } v;
  v.h = __float2bfloat16(f);
  return v.u;
}
__device__ __forceinline__ float bf2f(unsigned short u) {
  union { unsigned int i; float f; } x; x.i = ((unsigned int)u) << 16; return x.f;
}

// ---------------------------------------------------------------- fused prep: weight cvt + hq build
__global__ void k_misc(const float* __restrict__ w1, const float* __restrict__ w2,
                       const float* __restrict__ xyz2,
                       __hip_bfloat16* __restrict__ wb1, __hip_bfloat16* __restrict__ wb2,
                       float4* __restrict__ hq) {
  int i = blockIdx.x * 256 + threadIdx.x;
  if (i < 131072) {
    wb1[i] = __float2bfloat16(w1[i]);
  } else if (i < 196608) {
    int j = i - 131072;
    wb2[j] = __float2bfloat16(w2[j]);
  } else {
    int p = i - 196608;   // < 16384
    float x = xyz2[p * 3 + 0], y = xyz2[p * 3 + 1], z = xyz2[p * 3 + 2];
    float qq = __fadd_rn(__fadd_rn(__fmul_rn(x, x), __fmul_rn(y, y)), __fmul_rn(z, z));
    hq[p] = make_float4(x, y, z, qq);
  }
}

// ---------------------------------------------------------------- knn: 64 q/block, 8 waves x 256-chunk, branchless
__global__ __launch_bounds__(512, 4) void k_knn(const float* __restrict__ xyz1,
                                                const float4* __restrict__ hq,
                                                int* __restrict__ idx3, float* __restrict__ w3) {
  __shared__ float4 lhq[SSk];          // 32KB; merge arrays overlay after scan
  float* meP = (float*)lhq;            // [8][3][64] floats  (6144B)
  int*   miP = (int*)lhq + 1536;       // [8][3][64] ints    (6144B)
  int b = blockIdx.y;
  int t = threadIdx.x;
  int lane = t & 63, w = t >> 6;       // 8 waves

  const float4* __restrict__ hsrc = hq + (long)b * SSk;
#pragma unroll
  for (int j = 0; j < 4; ++j) lhq[t + j * 512] = hsrc[t + j * 512];

  int n = blockIdx.x * 64 + lane;
  long base = (long)(b * NNq + n);
  float x = xyz1[base * 3 + 0], y = xyz1[base * 3 + 1], z = xyz1[base * 3 + 2];
  float pp = __fadd_rn(__fadd_rn(__fmul_rn(x, x), __fmul_rn(y, y)), __fmul_rn(z, z));
  __syncthreads();

  float e0 = FLT_MAX, e1 = FLT_MAX, e2 = FLT_MAX;
  int i0 = 0, i1 = 0, i2 = 0;
  int s0 = w * 256;
#pragma unroll 4
  for (int i = 0; i < 256; ++i) {
    int s = s0 + i;
    float4 q = lhq[s];
    // d = ((-2*(x*qx + y*qy + z*qz)) + pp) + qq   -- exact np op order, no FMA
    float tt = __fadd_rn(__fadd_rn(__fmul_rn(x, q.x), __fmul_rn(y, q.y)), __fmul_rn(z, q.z));
    float d = __fadd_rn(__fadd_rn(__fmul_rn(-2.0f, tt), pp), q.w);
    // branchless sorted insert; strict < keeps earlier index on ties (np-stable)
    bool c0 = d < e0, c1 = d < e1, c2 = d < e2;
    int ni0 = c0 ? s : i0;
    int ni1 = c0 ? i0 : (c1 ? s : i1);
    int ni2 = c1 ? i1 : (c2 ? s : i2);
    i0 = ni0; i1 = ni1; i2 = ni2;
    float t0 = fminf(e0, d); float xx = fmaxf(e0, d); e0 = t0;
    float t1 = fminf(e1, xx); xx = fmaxf(e1, xx); e1 = t1;
    e2 = fminf(e2, xx);
  }
  __syncthreads();   // all waves done reading lhq; safe to overlay
  meP[(w * 3 + 0) * 64 + lane] = e0; meP[(w * 3 + 1) * 64 + lane] = e1; meP[(w * 3 + 2) * 64 + lane] = e2;
  miP[(w * 3 + 0) * 64 + lane] = i0; miP[(w * 3 + 1) * 64 + lane] = i1; miP[(w * 3 + 2) * 64 + lane] = i2;
  __syncthreads();

  if (w == 0) {
    // merge waves 1..7 in chunk order (ascending candidate ranges -> stable ties)
    for (int ww = 1; ww < 8; ++ww) {
#pragma unroll
      for (int k = 0; k < 3; ++k) {
        float d = meP[(ww * 3 + k) * 64 + lane]; int s = miP[(ww * 3 + k) * 64 + lane];
        if (d < e2) {
          if (d < e1) {
            e2 = e1; i2 = i1;
            if (d < e0) { e1 = e0; i1 = i0; e0 = d; i0 = s; }
            else        { e1 = d; i1 = s; }
          } else { e2 = d; i2 = s; }
        }
      }
    }
    float r0 = 1.f / (e0 + 1e-8f), r1 = 1.f / (e1 + 1e-8f), r2 = 1.f / (e2 + 1e-8f);
    float rs = r0 + r1 + r2;
    idx3[base * 3 + 0] = i0; idx3[base * 3 + 1] = i1; idx3[base * 3 + 2] = i2;
    w3[base * 3 + 0] = r0 / rs; w3[base * 3 + 1] = r1 / rs; w3[base * 3 + 2] = r2 / rs;
  }
}

// ---------------------------------------------------------------- transpose points1 -> xb[:,0:256] (bf16)
__global__ void k_tr_p1(const float* __restrict__ p1, __hip_bfloat16* __restrict__ xb) {
  __shared__ float tile[32][33];
  int b = blockIdx.z, c0 = blockIdx.y * 32, n0 = blockIdx.x * 32;
  int tx = threadIdx.x & 31, ty = threadIdx.x >> 5;   // 32x8
#pragma unroll
  for (int r = 0; r < 32; r += 8)
    tile[ty + r][tx] = p1[((long)(b * 256 + c0 + ty + r)) * NNq + n0 + tx];
  __syncthreads();
#pragma unroll
  for (int r = 0; r < 32; r += 8)
    xb[((long)(b * NNq + n0 + ty + r)) * CIN + c0 + tx] = __float2bfloat16(tile[tx][ty + r]);
}

// ---------------------------------------------------------------- transpose points2 -> p2t [B][S][256] f32
__global__ void k_tr_p2(const float* __restrict__ p2, float* __restrict__ p2t) {
  __shared__ float tile[32][33];
  int b = blockIdx.z, c0 = blockIdx.y * 32, s0 = blockIdx.x * 32;
  int tx = threadIdx.x & 31, ty = threadIdx.x >> 5;
#pragma unroll
  for (int r = 0; r < 32; r += 8)
    tile[ty + r][tx] = p2[((long)(b * 256 + c0 + ty + r)) * SSk + s0 + tx];
  __syncthreads();
#pragma unroll
  for (int r = 0; r < 32; r += 8)
    p2t[((long)(b * SSk + s0 + ty + r)) * 256 + c0 + tx] = tile[tx][ty + r];
}

// ---------------------------------------------------------------- gather + weighted interp -> xb[:,256:512]
__global__ void k_gather(const float* __restrict__ p2t, const int* __restrict__ idx3,
                         const float* __restrict__ w3, __hip_bfloat16* __restrict__ xb) {
  int b = blockIdx.y;
  int wid = threadIdx.x >> 6, lane = threadIdx.x & 63;
  int n = blockIdx.x * 4 + wid;                       // one wave per n
  long o = (long)(b * NNq + n) * 3;
  int i0 = idx3[o], i1 = idx3[o + 1], i2 = idx3[o + 2];
  float w0 = w3[o], w1 = w3[o + 1], w2 = w3[o + 2];
  const float4* r0 = (const float4*)(p2t + ((long)(b * SSk + i0)) * 256);
  const float4* r1 = (const float4*)(p2t + ((long)(b * SSk + i1)) * 256);
  const float4* r2 = (const float4*)(p2t + ((long)(b * SSk + i2)) * 256);
  float4 a = r0[lane], c = r1[lane], d = r2[lane];
  float vx = w0 * a.x + w1 * c.x + w2 * d.x;
  float vy = w0 * a.y + w1 * c.y + w2 * d.y;
  float vz = w0 * a.z + w1 * c.z + w2 * d.z;
  float vw = w0 * a.w + w1 * c.w + w2 * d.w;
  ushort4 u;
  u.x = f2bf(vx); u.y = f2bf(vy); u.z = f2bf(vz); u.w = f2bf(vw);
  *(ushort4*)((unsigned short*)xb + ((long)(b * NNq + n)) * CIN + 256 + lane * 4) = u;
}

// ---------------------------------------------------------------- GEMM (bf16 out) + fused BN partial stats
// X:[NR][K] bf16 K-major, W:[256][K] bf16 K-major, Yb:[NR][256] bf16.
// part: sums at part[ch*NBX+bx], sumsq at part[(256+ch)*NBX+bx]; bx = row-block.
// grid = dim3(2, NBX): consecutive blocks share the A-row panel (L2 reuse).
template <int K>
__global__ __launch_bounds__(256) void k_gemm(const __hip_bfloat16* __restrict__ X,
                                              const __hip_bfloat16* __restrict__ W,
                                              unsigned short* __restrict__ Yb,
                                              float* __restrict__ part) {
  constexpr int BK = 32;
  __shared__ __hip_bfloat16 xT[128 * BK];   // [row][k] row stride 32
  __shared__ __hip_bfloat16 wT[128 * BK];
  __shared__ float sb[4][4][16], qb[4][4][16];
  const int bx = blockIdx.y;
  const int r0 = bx * 128;
  const int c0 = blockIdx.x * 128;
  const int tid = threadIdx.x;
  const int wid = tid >> 6, lane = tid & 63;
  const int wr = wid >> 1, wc = wid & 1;    // 2x2 waves, each 64x64 out
  f32x4 acc[4][4] = {};

  for (int kt = 0; kt < K; kt += BK) {
#pragma unroll
    for (int jj = 0; jj < 2; ++jj) {
      int j = wid * 2 + jj;                 // 8 instrs cover 128 rows
      int row = j * 16 + (lane >> 2);
      const __hip_bfloat16* g = X + ((long)(r0 + row)) * K + kt + (lane & 3) * 8;
      __builtin_amdgcn_global_load_lds((const __attribute__((address_space(1))) void*)(const void*)g,
                                       (__attribute__((address_space(3))) void*)(void*)(xT + j * 512),
                                       16, 0, 0);
    }
#pragma unroll
    for (int jj = 0; jj < 2; ++jj) {
      int j = wid * 2 + jj;
      int row = j * 16 + (lane >> 2);
      const __hip_bfloat16* g = W + ((long)(c0 + row)) * K + kt + (lane & 3) * 8;
      __builtin_amdgcn_global_load_lds((const __attribute__((address_space(1))) void*)(const void*)g,
                                       (__attribute__((address_space(3))) void*)(void*)(wT + j * 512),
                                       16, 0, 0);
    }
    __syncthreads();

    bf16x8 af[4], bfr[4];
#pragma unroll
    for (int m = 0; m < 4; ++m) {
      int row = wr * 64 + m * 16 + (lane & 15);
      af[m] = *(const bf16x8*)(xT + row * BK + (lane >> 4) * 8);
    }
#pragma unroll
    for (int nn = 0; nn < 4; ++nn) {
      int row = wc * 64 + nn * 16 + (lane & 15);
      bfr[nn] = *(const bf16x8*)(wT + row * BK + (lane >> 4) * 8);
    }
#pragma unroll
    for (int m = 0; m < 4; ++m)
#pragma unroll
      for (int nn = 0; nn < 4; ++nn)
        acc[m][nn] = __builtin_amdgcn_mfma_f32_16x16x32_bf16(af[m], bfr[nn], acc[m][nn], 0, 0, 0);
    __syncthreads();
  }

  // C write (bf16)
#pragma unroll
  for (int m = 0; m < 4; ++m)
#pragma unroll
    for (int nn = 0; nn < 4; ++nn)
#pragma unroll
      for (int reg = 0; reg < 4; ++reg) {
        int r = r0 + wr * 64 + m * 16 + (lane >> 4) * 4 + reg;
        int c = c0 + wc * 64 + nn * 16 + (lane & 15);
        Yb[(long)r * OC + c] = f2bf(acc[m][nn][reg]);
      }

  // fused BN partial stats: per-channel sum & sumsq over this block's 128 rows (f32-exact)
#pragma unroll
  for (int nn = 0; nn < 4; ++nn) {
    float s = 0.f, q = 0.f;
#pragma unroll
    for (int m = 0; m < 4; ++m)
#pragma unroll
      for (int reg = 0; reg < 4; ++reg) {
        float v = acc[m][nn][reg];
        s += v; q += v * v;
      }
    s += __shfl_xor(s, 16); s += __shfl_xor(s, 32);
    q += __shfl_xor(q, 16); q += __shfl_xor(q, 32);
    if (lane < 16) { sb[wid][nn][lane] = s; qb[wid][nn][lane] = q; }
  }
  __syncthreads();
  if (tid < 128) {
    int col = tid & 15, nn = (tid >> 4) & 3, wcc = (tid >> 6) & 1;
    float s = sb[wcc][nn][col] + sb[2 + wcc][nn][col];   // wid = wr*2+wc
    float q = qb[wcc][nn][col] + qb[2 + wcc][nn][col];
    int ch = c0 + wcc * 64 + nn * 16 + col;
    part[(long)ch * NBX + bx] = s;
    part[(long)(256 + ch) * NBX + bx] = q;
  }
}

// ---------------------------------------------------------------- reduce partials, finalize BN scale/shift
__global__ void k_scalefix(const float* __restrict__ part, const float* __restrict__ g,
                           const float* __restrict__ be, float* __restrict__ st) {
  int o = threadIdx.x;
  const float4* ps = (const float4*)(part + (long)o * NBX);
  const float4* pq = (const float4*)(part + (long)(256 + o) * NBX);
  float s = 0.f, q = 0.f;
#pragma unroll 8
  for (int i = 0; i < NBX / 4; ++i) {
    float4 a = ps[i], bq = pq[i];
    s += (a.x + a.y) + (a.z + a.w);
    q += (bq.x + bq.y) + (bq.z + bq.w);
  }
  float mean = s * (1.f / NR);
  float var = q * (1.f / NR) - mean * mean;
  float sc = g[o] * rsqrtf(var + 1e-5f);
  st[o] = sc;
  st[OC + o] = be[o] - mean * sc;
}

// ---------------------------------------------------------------- BN+ReLU: bf16 in -> bf16 out
__global__ void k_bnrelu_bf16(const unsigned short* __restrict__ Y, const float* __restrict__ st,
                              unsigned short* __restrict__ Yb) {
  long i8 = (long)blockIdx.x * 256 + threadIdx.x;   // ushort8 index over [NR*256/8]
  ushort8 v = ((const ushort8*)Y)[i8];
  int c8 = (int)(i8 & 31);                           // channel-group (256/8)
  float4 sca = ((const float4*)st)[c8 * 2];
  float4 scb = ((const float4*)st)[c8 * 2 + 1];
  float4 sha = ((const float4*)(st + OC))[c8 * 2];
  float4 shb = ((const float4*)(st + OC))[c8 * 2 + 1];
  ushort8 u;
  u[0] = f2bf(fmaxf(fmaf(bf2f(v[0]), sca.x, sha.x), 0.f));
  u[1] = f2bf(fmaxf(fmaf(bf2f(v[1]), sca.y, sha.y), 0.f));
  u[2] = f2bf(fmaxf(fmaf(bf2f(v[2]), sca.z, sha.z), 0.f));
  u[3] = f2bf(fmaxf(fmaf(bf2f(v[3]), sca.w, sha.w), 0.f));
  u[4] = f2bf(fmaxf(fmaf(bf2f(v[4]), scb.x, shb.x), 0.f));
  u[5] = f2bf(fmaxf(fmaf(bf2f(v[5]), scb.y, shb.y), 0.f));
  u[6] = f2bf(fmaxf(fmaf(bf2f(v[6]), scb.z, shb.z), 0.f));
  u[7] = f2bf(fmaxf(fmaf(bf2f(v[7]), scb.w, shb.w), 0.f));
  ((ushort8*)Yb)[i8] = u;
}

// ---------------------------------------------------------------- BN+ReLU + transpose -> out [B][256][N] f32
__global__ void k_final(const unsigned short* __restrict__ Y, const float* __restrict__ st,
                        float* __restrict__ out) {
  __shared__ float tile[32][33];
  int b = blockIdx.z, o0 = blockIdx.y * 32, n0 = blockIdx.x * 32;
  int tx = threadIdx.x & 31, ty = threadIdx.x >> 5;
  float sc = st[o0 + tx], sh = st[OC + o0 + tx];
#pragma unroll
  for (int r = 0; r < 32; r += 8) {
    float v = bf2f(Y[((long)(b * NNq + n0 + ty + r)) * OC + o0 + tx]);
    tile[ty + r][tx] = fmaxf(fmaf(v, sc, sh), 0.f);
  }
  __syncthreads();
#pragma unroll
  for (int r = 0; r < 32; r += 8)
    out[((long)(b * 256 + o0 + ty + r)) * NNq + n0 + tx] = tile[tx][ty + r];
}

// ================================================================ launch
extern "C" void kernel_launch(void* const* d_in, const int* in_sizes, int n_in,
                              void* d_out, int out_size, void* d_ws, size_t ws_size,
                              hipStream_t stream) {
  const float* xyz1 = (const float*)d_in[0];
  const float* xyz2 = (const float*)d_in[1];
  const float* p1   = (const float*)d_in[2];
  const float* p2   = (const float*)d_in[3];
  const float* w1   = (const float*)d_in[4];
  // d_in[5] = b1 : cancels exactly under batch-norm mean subtraction
  const float* g1   = (const float*)d_in[6];
  const float* be1  = (const float*)d_in[7];
  const float* w2   = (const float*)d_in[8];
  // d_in[9] = b2 : cancels
  const float* g2   = (const float*)d_in[10];
  const float* be2  = (const float*)d_in[11];
  float* out = (float*)d_out;    // reference output dtype is float32

  char* ws = (char*)d_ws;
  // layout (bytes):
  //   XB   65536*512*2 = 67108864   (reused by Y1B after GEMM1)
  //   Y1   65536*256*2 = 33554432 bf16  (P2T 16MB f32 aliases its head pre-GEMM1; Y2 aliases after bnrelu)
  //   HQ   16384*16    =   262144
  //   IDX  65536*3*4   =   786432   (dead after k_gather -> reused by PART 1MB)
  //   W3   65536*3*4   =   786432
  //   WB1/WB2/ST1/ST2 as below
  const size_t OFF_XB   = 0;
  const size_t OFF_Y1   = 67108864;
  const size_t OFF_P2T  = OFF_Y1;                  // dead before GEMM1 writes Y1
  const size_t OFF_MISC = 134217728;
  const size_t OFF_HQ   = OFF_MISC + 0;
  const size_t OFF_IDX  = OFF_MISC + 262144;
  const size_t OFF_W3   = OFF_MISC + 1048576;
  const size_t OFF_WB1  = OFF_MISC + 1835008;
  const size_t OFF_WB2  = OFF_MISC + 2097152;
  const size_t OFF_ST1  = OFF_MISC + 2228224;
  const size_t OFF_ST2  = OFF_MISC + 2230272;
  const size_t OFF_PART = OFF_IDX;                 // 1MB, aliases idx3+w3 (dead after k_gather)

  __hip_bfloat16* xb   = (__hip_bfloat16*)(ws + OFF_XB);
  unsigned short* y1   = (unsigned short*)(ws + OFF_Y1);   // bf16
  unsigned short* y2   = (unsigned short*)(ws + OFF_Y1);   // alias: y1 dead after bnrelu
  float* p2t           = (float*)(ws + OFF_P2T);
  float4* hq           = (float4*)(ws + OFF_HQ);
  int*   idx3          = (int*)(ws + OFF_IDX);
  float* w3            = (float*)(ws + OFF_W3);
  __hip_bfloat16* wb1  = (__hip_bfloat16*)(ws + OFF_WB1);
  __hip_bfloat16* wb2  = (__hip_bfloat16*)(ws + OFF_WB2);
  unsigned short* y1b  = (unsigned short*)(ws + OFF_XB);   // alias: xb dead after GEMM1
  float* st1           = (float*)(ws + OFF_ST1);
  float* st2           = (float*)(ws + OFF_ST2);
  float* part          = (float*)(ws + OFF_PART);

  k_misc<<<832, 256, 0, stream>>>(w1, w2, xyz2, wb1, wb2, hq);
  k_knn<<<dim3(NNq / 64, BB), 512, 0, stream>>>(xyz1, hq, idx3, w3);
  k_tr_p1<<<dim3(NNq / 32, 256 / 32, BB), 256, 0, stream>>>(p1, xb);
  k_tr_p2<<<dim3(SSk / 32, 256 / 32, BB), 256, 0, stream>>>(p2, p2t);
  k_gather<<<dim3(NNq / 4, BB), 256, 0, stream>>>(p2t, idx3, w3, xb);

  k_gemm<512><<<dim3(2, NBX), 256, 0, stream>>>(xb, wb1, y1, part);
  k_scalefix<<<1, 256, 0, stream>>>(part, g1, be1, st1);
  k_bnrelu_bf16<<<(int)((long)NR * 256 / 8 / 256), 256, 0, stream>>>(y1, st1, y1b);

  k_gemm<256><<<dim3(2, NBX), 256, 0, stream>>>((const __hip_bfloat16*)y1b, wb2, y2, part);
  k_scalefix<<<1, 256, 0, stream>>>(part, g2, be2, st2);
  k_final<<<dim3(NNq / 32, 256 / 32, BB), 256, 0, stream>>>(y2, st2, out);

  (void)in_sizes; (void)n_in; (void)out_size; (void)ws_size;
}

// Round 7
// 253.654 us; speedup vs baseline: 1.6616x; 1.0552x over previous
//
#include <hip/hip_runtime.h>
#include <hip/hip_bf16.h>
#include <float.h>

#define BB 8
#define NNq 8192
#define SSk 2048
#define CIN 512
#define OC 256
#define NR (BB * NNq)   // 65536 total rows (b*N+n)
#define NBX 512         // GEMM row-blocks = NR/128

typedef __attribute__((ext_vector_type(8))) short bf16x8;
typedef __attribute__((ext_vector_type(8))) unsigned short ushort8;
typedef __attribute__((ext_vector_type(4))) float f32x4;

__device__ __forceinline__ unsigned short f2bf(float f) {
  union { __hip_bfloat16 h; unsigned short u; } v;
  v.h = __float2bfloat16(f);
  return v.u;
}
__device__ __forceinline__ float bf2f(unsigned short u) {
  union { unsigned int i; float f; } x; x.i = ((unsigned int)u) << 16; return x.f;
}

// ---------------------------------------------------------------- fused prep: weight cvt + hq build
__global__ void k_misc(const float* __restrict__ w1, const float* __restrict__ w2,
                       const float* __restrict__ xyz2,
                       __hip_bfloat16* __restrict__ wb1, __hip_bfloat16* __restrict__ wb2,
                       float4* __restrict__ hq) {
  int i = blockIdx.x * 256 + threadIdx.x;
  if (i < 131072) {
    wb1[i] = __float2bfloat16(w1[i]);
  } else if (i < 196608) {
    int j = i - 131072;
    wb2[j] = __float2bfloat16(w2[j]);
  } else {
    int p = i - 196608;   // < 16384
    float x = xyz2[p * 3 + 0], y = xyz2[p * 3 + 1], z = xyz2[p * 3 + 2];
    float qq = __fadd_rn(__fadd_rn(__fmul_rn(x, x), __fmul_rn(y, y)), __fmul_rn(z, z));
    hq[p] = make_float4(x, y, z, qq);
  }
}

// ---------------------------------------------------------------- knn: 64 q/block, 8 waves x 256-chunk
// lean branchless insert: values via fmed3, indices via nested cndmask
__global__ __launch_bounds__(512) void k_knn(const float* __restrict__ xyz1,
                                             const float4* __restrict__ hq,
                                             int* __restrict__ idx3, float* __restrict__ w3) {
  __shared__ float4 lhq[SSk];          // 32KB; merge arrays overlay after scan
  float* meP = (float*)lhq;            // [8][3][64] floats  (6144B)
  int*   miP = (int*)lhq + 1536;       // [8][3][64] ints    (6144B)
  int b = blockIdx.y;
  int t = threadIdx.x;
  int lane = t & 63, w = t >> 6;       // 8 waves

  const float4* __restrict__ hsrc = hq + (long)b * SSk;
#pragma unroll
  for (int j = 0; j < 4; ++j) lhq[t + j * 512] = hsrc[t + j * 512];

  int n = blockIdx.x * 64 + lane;
  long base = (long)(b * NNq + n);
  float x = xyz1[base * 3 + 0], y = xyz1[base * 3 + 1], z = xyz1[base * 3 + 2];
  float pp = __fadd_rn(__fadd_rn(__fmul_rn(x, x), __fmul_rn(y, y)), __fmul_rn(z, z));
  __syncthreads();

  float e0 = FLT_MAX, e1 = FLT_MAX, e2 = FLT_MAX;
  int i0 = 0, i1 = 0, i2 = 0;
  const float4* __restrict__ qp = lhq + w * 256;
#pragma unroll 4
  for (int ii = 0; ii < 256; ++ii) {
    float4 q = qp[ii];
    // d = ((-2*(x*qx + y*qy + z*qz)) + pp) + qq   -- exact np op order, no FMA
    float tt = __fadd_rn(__fadd_rn(__fmul_rn(x, q.x), __fmul_rn(y, q.y)), __fmul_rn(z, q.z));
    float d = __fadd_rn(__fadd_rn(__fmul_rn(-2.0f, tt), pp), q.w);
    // strict < keeps earlier index on ties (np-stable)
    bool c0 = d < e0, c1 = d < e1, c2 = d < e2;
    int ni2 = c1 ? i1 : (c2 ? ii : i2);
    int ni1 = c0 ? i0 : (c1 ? ii : i1);
    int ni0 = c0 ? ii : i0;
    float ne2 = __builtin_amdgcn_fmed3f(d, e1, e2);   // median(old e1, old e2, d)
    float ne1 = __builtin_amdgcn_fmed3f(d, e0, e1);
    e0 = fminf(e0, d);
    e1 = ne1; e2 = ne2; i0 = ni0; i1 = ni1; i2 = ni2;
  }
  __syncthreads();   // all waves done reading lhq; safe to overlay
  int s0 = w * 256;
  meP[(w * 3 + 0) * 64 + lane] = e0; meP[(w * 3 + 1) * 64 + lane] = e1; meP[(w * 3 + 2) * 64 + lane] = e2;
  miP[(w * 3 + 0) * 64 + lane] = i0 + s0; miP[(w * 3 + 1) * 64 + lane] = i1 + s0; miP[(w * 3 + 2) * 64 + lane] = i2 + s0;
  __syncthreads();

  if (w == 0) {
    int gi0 = i0, gi1 = i1, gi2 = i2;   // wave0: s0 == 0
    // merge waves 1..7 in chunk order (ascending candidate ranges -> stable ties)
    for (int ww = 1; ww < 8; ++ww) {
#pragma unroll
      for (int k = 0; k < 3; ++k) {
        float d = meP[(ww * 3 + k) * 64 + lane]; int s = miP[(ww * 3 + k) * 64 + lane];
        bool c0 = d < e0, c1 = d < e1, c2 = d < e2;
        int ni2 = c1 ? gi1 : (c2 ? s : gi2);
        int ni1 = c0 ? gi0 : (c1 ? s : gi1);
        int ni0 = c0 ? s : gi0;
        float ne2 = __builtin_amdgcn_fmed3f(d, e1, e2);
        float ne1 = __builtin_amdgcn_fmed3f(d, e0, e1);
        e0 = fminf(e0, d);
        e1 = ne1; e2 = ne2; gi0 = ni0; gi1 = ni1; gi2 = ni2;
      }
    }
    float r0 = 1.f / (e0 + 1e-8f), r1 = 1.f / (e1 + 1e-8f), r2 = 1.f / (e2 + 1e-8f);
    float rs = r0 + r1 + r2;
    idx3[base * 3 + 0] = gi0; idx3[base * 3 + 1] = gi1; idx3[base * 3 + 2] = gi2;
    w3[base * 3 + 0] = r0 / rs; w3[base * 3 + 1] = r1 / rs; w3[base * 3 + 2] = r2 / rs;
  }
}

// ---------------------------------------------------------------- transpose points1 -> xb[:,0:256] (bf16)
__global__ void k_tr_p1(const float* __restrict__ p1, __hip_bfloat16* __restrict__ xb) {
  __shared__ float tile[32][33];
  int b = blockIdx.z, c0 = blockIdx.y * 32, n0 = blockIdx.x * 32;
  int tx = threadIdx.x & 31, ty = threadIdx.x >> 5;   // 32x8
#pragma unroll
  for (int r = 0; r < 32; r += 8)
    tile[ty + r][tx] = p1[((long)(b * 256 + c0 + ty + r)) * NNq + n0 + tx];
  __syncthreads();
#pragma unroll
  for (int r = 0; r < 32; r += 8)
    xb[((long)(b * NNq + n0 + ty + r)) * CIN + c0 + tx] = __float2bfloat16(tile[tx][ty + r]);
}

// ---------------------------------------------------------------- transpose points2 -> p2t [B][S][256] f32
__global__ void k_tr_p2(const float* __restrict__ p2, float* __restrict__ p2t) {
  __shared__ float tile[32][33];
  int b = blockIdx.z, c0 = blockIdx.y * 32, s0 = blockIdx.x * 32;
  int tx = threadIdx.x & 31, ty = threadIdx.x >> 5;
#pragma unroll
  for (int r = 0; r < 32; r += 8)
    tile[ty + r][tx] = p2[((long)(b * 256 + c0 + ty + r)) * SSk + s0 + tx];
  __syncthreads();
#pragma unroll
  for (int r = 0; r < 32; r += 8)
    p2t[((long)(b * SSk + s0 + ty + r)) * 256 + c0 + tx] = tile[tx][ty + r];
}

// ---------------------------------------------------------------- gather + weighted interp -> xb[:,256:512]
__global__ void k_gather(const float* __restrict__ p2t, const int* __restrict__ idx3,
                         const float* __restrict__ w3, __hip_bfloat16* __restrict__ xb) {
  int b = blockIdx.y;
  int wid = threadIdx.x >> 6, lane = threadIdx.x & 63;
  int n = blockIdx.x * 4 + wid;                       // one wave per n
  long o = (long)(b * NNq + n) * 3;
  int i0 = idx3[o], i1 = idx3[o + 1], i2 = idx3[o + 2];
  float w0 = w3[o], w1 = w3[o + 1], w2 = w3[o + 2];
  const float4* r0 = (const float4*)(p2t + ((long)(b * SSk + i0)) * 256);
  const float4* r1 = (const float4*)(p2t + ((long)(b * SSk + i1)) * 256);
  const float4* r2 = (const float4*)(p2t + ((long)(b * SSk + i2)) * 256);
  float4 a = r0[lane], c = r1[lane], d = r2[lane];
  float vx = w0 * a.x + w1 * c.x + w2 * d.x;
  float vy = w0 * a.y + w1 * c.y + w2 * d.y;
  float vz = w0 * a.z + w1 * c.z + w2 * d.z;
  float vw = w0 * a.w + w1 * c.w + w2 * d.w;
  ushort4 u;
  u.x = f2bf(vx); u.y = f2bf(vy); u.z = f2bf(vz); u.w = f2bf(vw);
  *(ushort4*)((unsigned short*)xb + ((long)(b * NNq + n)) * CIN + 256 + lane * 4) = u;
}

// ---------------------------------------------------------------- GEMM (bf16 out) + fused BN partial stats
// 1-D grid of 2*NBX, XCD-pair swizzle: the two col-blocks of one row-panel are
// placed 8 dispatch-ids apart -> same XCD (id%8) -> A-panel L2 reuse.
template <int K>
__global__ __launch_bounds__(256) void k_gemm(const __hip_bfloat16* __restrict__ X,
                                              const __hip_bfloat16* __restrict__ W,
                                              unsigned short* __restrict__ Yb,
                                              float* __restrict__ part) {
  constexpr int BK = 32;
  __shared__ __hip_bfloat16 xT[128 * BK];   // [row][k] row stride 32
  __shared__ __hip_bfloat16 wT[128 * BK];
  __shared__ float sb[4][4][16], qb[4][4][16];
  const int id = blockIdx.x;
  const int super = id >> 4, slot = id & 15;
  const int bx = super * 8 + (slot & 7);    // row-panel 0..NBX-1
  const int r0 = bx * 128;
  const int c0 = (slot >> 3) * 128;         // col 0 or 128
  const int tid = threadIdx.x;
  const int wid = tid >> 6, lane = tid & 63;
  const int wr = wid >> 1, wc = wid & 1;    // 2x2 waves, each 64x64 out
  f32x4 acc[4][4] = {};

  for (int kt = 0; kt < K; kt += BK) {
#pragma unroll
    for (int jj = 0; jj < 2; ++jj) {
      int j = wid * 2 + jj;                 // 8 instrs cover 128 rows
      int row = j * 16 + (lane >> 2);
      const __hip_bfloat16* g = X + ((long)(r0 + row)) * K + kt + (lane & 3) * 8;
      __builtin_amdgcn_global_load_lds((const __attribute__((address_space(1))) void*)(const void*)g,
                                       (__attribute__((address_space(3))) void*)(void*)(xT + j * 512),
                                       16, 0, 0);
    }
#pragma unroll
    for (int jj = 0; jj < 2; ++jj) {
      int j = wid * 2 + jj;
      int row = j * 16 + (lane >> 2);
      const __hip_bfloat16* g = W + ((long)(c0 + row)) * K + kt + (lane & 3) * 8;
      __builtin_amdgcn_global_load_lds((const __attribute__((address_space(1))) void*)(const void*)g,
                                       (__attribute__((address_space(3))) void*)(void*)(wT + j * 512),
                                       16, 0, 0);
    }
    __syncthreads();

    bf16x8 af[4], bfr[4];
#pragma unroll
    for (int m = 0; m < 4; ++m) {
      int row = wr * 64 + m * 16 + (lane & 15);
      af[m] = *(const bf16x8*)(xT + row * BK + (lane >> 4) * 8);
    }
#pragma unroll
    for (int nn = 0; nn < 4; ++nn) {
      int row = wc * 64 + nn * 16 + (lane & 15);
      bfr[nn] = *(const bf16x8*)(wT + row * BK + (lane >> 4) * 8);
    }
#pragma unroll
    for (int m = 0; m < 4; ++m)
#pragma unroll
      for (int nn = 0; nn < 4; ++nn)
        acc[m][nn] = __builtin_amdgcn_mfma_f32_16x16x32_bf16(af[m], bfr[nn], acc[m][nn], 0, 0, 0);
    __syncthreads();
  }

  // C write (bf16)
#pragma unroll
  for (int m = 0; m < 4; ++m)
#pragma unroll
    for (int nn = 0; nn < 4; ++nn)
#pragma unroll
      for (int reg = 0; reg < 4; ++reg) {
        int r = r0 + wr * 64 + m * 16 + (lane >> 4) * 4 + reg;
        int c = c0 + wc * 64 + nn * 16 + (lane & 15);
        Yb[(long)r * OC + c] = f2bf(acc[m][nn][reg]);
      }

  // fused BN partial stats: per-channel sum & sumsq over this block's 128 rows (f32-exact)
#pragma unroll
  for (int nn = 0; nn < 4; ++nn) {
    float s = 0.f, q = 0.f;
#pragma unroll
    for (int m = 0; m < 4; ++m)
#pragma unroll
      for (int reg = 0; reg < 4; ++reg) {
        float v = acc[m][nn][reg];
        s += v; q += v * v;
      }
    s += __shfl_xor(s, 16); s += __shfl_xor(s, 32);
    q += __shfl_xor(q, 16); q += __shfl_xor(q, 32);
    if (lane < 16) { sb[wid][nn][lane] = s; qb[wid][nn][lane] = q; }
  }
  __syncthreads();
  if (tid < 128) {
    int col = tid & 15, nn = (tid >> 4) & 3, wcc = (tid >> 6) & 1;
    float s = sb[wcc][nn][col] + sb[2 + wcc][nn][col];   // wid = wr*2+wc
    float q = qb[wcc][nn][col] + qb[2 + wcc][nn][col];
    int ch = c0 + wcc * 64 + nn * 16 + col;
    part[(long)ch * NBX + bx] = s;
    part[(long)(256 + ch) * NBX + bx] = q;
  }
}

// ---------------------------------------------------------------- reduce partials, finalize BN scale/shift
__global__ void k_scalefix(const float* __restrict__ part, const float* __restrict__ g,
                           const float* __restrict__ be, float* __restrict__ st) {
  int o = threadIdx.x;
  const float4* ps = (const float4*)(part + (long)o * NBX);
  const float4* pq = (const float4*)(part + (long)(256 + o) * NBX);
  float s = 0.f, q = 0.f;
#pragma unroll 8
  for (int i = 0; i < NBX / 4; ++i) {
    float4 a = ps[i], bq = pq[i];
    s += (a.x + a.y) + (a.z + a.w);
    q += (bq.x + bq.y) + (bq.z + bq.w);
  }
  float mean = s * (1.f / NR);
  float var = q * (1.f / NR) - mean * mean;
  float sc = g[o] * rsqrtf(var + 1e-5f);
  st[o] = sc;
  st[OC + o] = be[o] - mean * sc;
}

// ---------------------------------------------------------------- BN+ReLU: bf16 in -> bf16 out
__global__ void k_bnrelu_bf16(const unsigned short* __restrict__ Y, const float* __restrict__ st,
                              unsigned short* __restrict__ Yb) {
  long i8 = (long)blockIdx.x * 256 + threadIdx.x;   // ushort8 index over [NR*256/8]
  ushort8 v = ((const ushort8*)Y)[i8];
  int c8 = (int)(i8 & 31);                           // channel-group (256/8)
  float4 sca = ((const float4*)st)[c8 * 2];
  float4 scb = ((const float4*)st)[c8 * 2 + 1];
  float4 sha = ((const float4*)(st + OC))[c8 * 2];
  float4 shb = ((const float4*)(st + OC))[c8 * 2 + 1];
  ushort8 u;
  u[0] = f2bf(fmaxf(fmaf(bf2f(v[0]), sca.x, sha.x), 0.f));
  u[1] = f2bf(fmaxf(fmaf(bf2f(v[1]), sca.y, sha.y), 0.f));
  u[2] = f2bf(fmaxf(fmaf(bf2f(v[2]), sca.z, sha.z), 0.f));
  u[3] = f2bf(fmaxf(fmaf(bf2f(v[3]), sca.w, sha.w), 0.f));
  u[4] = f2bf(fmaxf(fmaf(bf2f(v[4]), scb.x, shb.x), 0.f));
  u[5] = f2bf(fmaxf(fmaf(bf2f(v[5]), scb.y, shb.y), 0.f));
  u[6] = f2bf(fmaxf(fmaf(bf2f(v[6]), scb.z, shb.z), 0.f));
  u[7] = f2bf(fmaxf(fmaf(bf2f(v[7]), scb.w, shb.w), 0.f));
  ((ushort8*)Yb)[i8] = u;
}

// ---------------------------------------------------------------- BN+ReLU + transpose -> out [B][256][N] f32
// tile 32c x 256n; ushort2 loads, float4 full-wave stores
__global__ void k_final(const unsigned short* __restrict__ Y, const float* __restrict__ st,
                        float* __restrict__ out) {
  __shared__ float tile[256][33];            // [n_local][c_local]
  int b = blockIdx.z, o0 = blockIdx.y * 32, n0 = blockIdx.x * 256;
  int t = threadIdx.x;
  int cp = t & 15, tn = t >> 4;              // 16 c-pairs x 16 rows
  int c = cp * 2;
  float sc0 = st[o0 + c], sc1 = st[o0 + c + 1];
  float sh0 = st[OC + o0 + c], sh1 = st[OC + o0 + c + 1];
#pragma unroll
  for (int r = 0; r < 16; ++r) {
    int nl = r * 16 + tn;
    ushort2 v = *(const ushort2*)(Y + ((long)(b * NNq + n0 + nl)) * OC + o0 + c);
    tile[nl][c]     = fmaxf(fmaf(bf2f(v.x), sc0, sh0), 0.f);
    tile[nl][c + 1] = fmaxf(fmaf(bf2f(v.y), sc1, sh1), 0.f);
  }
  __syncthreads();
  int w = t >> 6, lane = t & 63;             // 4 waves x 8 c-rows each
#pragma unroll
  for (int rr = 0; rr < 8; ++rr) {
    int cl = w * 8 + rr;
    float4 v = make_float4(tile[lane * 4 + 0][cl], tile[lane * 4 + 1][cl],
                           tile[lane * 4 + 2][cl], tile[lane * 4 + 3][cl]);
    *(float4*)(out + ((long)(b * 256 + o0 + cl)) * NNq + n0 + lane * 4) = v;
  }
}

// ================================================================ launch
extern "C" void kernel_launch(void* const* d_in, const int* in_sizes, int n_in,
                              void* d_out, int out_size, void* d_ws, size_t ws_size,
                              hipStream_t stream) {
  const float* xyz1 = (const float*)d_in[0];
  const float* xyz2 = (const float*)d_in[1];
  const float* p1   = (const float*)d_in[2];
  const float* p2   = (const float*)d_in[3];
  const float* w1   = (const float*)d_in[4];
  // d_in[5] = b1 : cancels exactly under batch-norm mean subtraction
  const float* g1   = (const float*)d_in[6];
  const float* be1  = (const float*)d_in[7];
  const float* w2   = (const float*)d_in[8];
  // d_in[9] = b2 : cancels
  const float* g2   = (const float*)d_in[10];
  const float* be2  = (const float*)d_in[11];
  float* out = (float*)d_out;    // reference output dtype is float32

  char* ws = (char*)d_ws;
  const size_t OFF_XB   = 0;
  const size_t OFF_Y1   = 67108864;
  const size_t OFF_P2T  = OFF_Y1;                  // dead before GEMM1 writes Y1
  const size_t OFF_MISC = 134217728;
  const size_t OFF_HQ   = OFF_MISC + 0;
  const size_t OFF_IDX  = OFF_MISC + 262144;
  const size_t OFF_W3   = OFF_MISC + 1048576;
  const size_t OFF_WB1  = OFF_MISC + 1835008;
  const size_t OFF_WB2  = OFF_MISC + 2097152;
  const size_t OFF_ST1  = OFF_MISC + 2228224;
  const size_t OFF_ST2  = OFF_MISC + 2230272;
  const size_t OFF_PART = OFF_IDX;                 // 1MB, aliases idx3+w3 (dead after k_gather)

  __hip_bfloat16* xb   = (__hip_bfloat16*)(ws + OFF_XB);
  unsigned short* y1   = (unsigned short*)(ws + OFF_Y1);   // bf16
  unsigned short* y2   = (unsigned short*)(ws + OFF_Y1);   // alias: y1 dead after bnrelu
  float* p2t           = (float*)(ws + OFF_P2T);
  float4* hq           = (float4*)(ws + OFF_HQ);
  int*   idx3          = (int*)(ws + OFF_IDX);
  float* w3            = (float*)(ws + OFF_W3);
  __hip_bfloat16* wb1  = (__hip_bfloat16*)(ws + OFF_WB1);
  __hip_bfloat16* wb2  = (__hip_bfloat16*)(ws + OFF_WB2);
  unsigned short* y1b  = (unsigned short*)(ws + OFF_XB);   // alias: xb dead after GEMM1
  float* st1           = (float*)(ws + OFF_ST1);
  float* st2           = (float*)(ws + OFF_ST2);
  float* part          = (float*)(ws + OFF_PART);

  k_misc<<<832, 256, 0, stream>>>(w1, w2, xyz2, wb1, wb2, hq);
  k_knn<<<dim3(NNq / 64, BB), 512, 0, stream>>>(xyz1, hq, idx3, w3);
  k_tr_p1<<<dim3(NNq / 32, 256 / 32, BB), 256, 0, stream>>>(p1, xb);
  k_tr_p2<<<dim3(SSk / 32, 256 / 32, BB), 256, 0, stream>>>(p2, p2t);
  k_gather<<<dim3(NNq / 4, BB), 256, 0, stream>>>(p2t, idx3, w3, xb);

  k_gemm<512><<<2 * NBX, 256, 0, stream>>>(xb, wb1, y1, part);
  k_scalefix<<<1, 256, 0, stream>>>(part, g1, be1, st1);
  k_bnrelu_bf16<<<(int)((long)NR * 256 / 8 / 256), 256, 0, stream>>>(y1, st1, y1b);

  k_gemm<256><<<2 * NBX, 256, 0, stream>>>((const __hip_bfloat16*)y1b, wb2, y2, part);
  k_scalefix<<<1, 256, 0, stream>>>(part, g2, be2, st2);
  k_final<<<dim3(NNq / 256, 256 / 32, BB), 256, 0, stream>>>(y2, st2, out);

  (void)in_sizes; (void)n_in; (void)out_size; (void)ws_size;
}